// Round 2
// baseline (197.382 us; speedup 1.0000x reference)
//
#include <hip/hip_runtime.h>
#include <math.h>

#define BB 32
#define NN 8732
#define CC 21
#define TOPK 200
#define NPOSE 32
#define NLINE 3
#define NBINS 2048
#define CAP 4096
#define ROWW 40

// ---------------------------------------------------------------------------
// Exact-f32 softmax stats: f32 max; correctly-rounded-f32 exp of the exact f32
// difference; numpy pairwise-8 summation order for n=21 (r[j]=e[j]+e[8+j],
// combine ((r0+r1)+(r2+r3))+((r4+r5)+(r6+r7)), then += e[16..20] sequential).
// ---------------------------------------------------------------------------
__device__ inline void softmax_es(const float* __restrict__ p, float* e, float& sumOut) {
  float m = p[0];
#pragma unroll
  for (int c = 1; c < CC; ++c) m = fmaxf(m, p[c]);
#pragma unroll
  for (int c = 0; c < CC; ++c) e[c] = (float)exp((double)(p[c] - m));
  float r0 = e[0] + e[8], r1 = e[1] + e[9], r2 = e[2] + e[10], r3 = e[3] + e[11];
  float r4 = e[4] + e[12], r5 = e[5] + e[13], r6 = e[6] + e[14], r7 = e[7] + e[15];
  float res = ((r0 + r1) + (r2 + r3)) + ((r4 + r5) + (r6 + r7));
  res += e[16]; res += e[17]; res += e[18]; res += e[19]; res += e[20];
  sumOut = res;
}

// ---------------------------------------------------------------------------
// Mode 2 precompute: scores[b][c][n] (transposed for coalesced per-class reads)
// ---------------------------------------------------------------------------
__global__ __launch_bounds__(256) void score_kernel(
    const float* __restrict__ conf, float* __restrict__ scores) {
  int i = blockIdx.x * 256 + threadIdx.x;  // b*NN + n
  if (i >= BB * NN) return;
  int b = i / NN, n = i - b * NN;
  const float* p = conf + (size_t)i * CC;
  float e[CC], sum;
  softmax_es(p, e, sum);
#pragma unroll
  for (int c = 0; c < CC; ++c)
    scores[((size_t)b * CC + c) * NN + n] = e[c] / sum;  // f32 divide, exact IEEE
}

// ---------------------------------------------------------------------------
// Mode 1 precompute: aux[b*NN+n] = (max, sum)
// ---------------------------------------------------------------------------
__global__ __launch_bounds__(256) void aux_kernel(
    const float* __restrict__ conf, float2* __restrict__ aux) {
  int i = blockIdx.x * 256 + threadIdx.x;
  if (i >= BB * NN) return;
  const float* p = conf + (size_t)i * CC;
  float e[CC], sum;
  softmax_es(p, e, sum);
  float m = p[0];
#pragma unroll
  for (int c = 1; c < CC; ++c) m = fmaxf(m, p[c]);
  aux[i] = make_float2(m, sum);
}

// ---------------------------------------------------------------------------
// One block per (b,c): exact top-200 (f32 keys) + greedy NMS + row assembly.
// All arithmetic simulated in f32 exactly as the numpy/jax f32 pipeline.
// ---------------------------------------------------------------------------
__global__ __launch_bounds__(256) void nms_kernel(
    const float* __restrict__ loc, const float* __restrict__ conf,
    const float* __restrict__ pose, const float* __restrict__ line,
    const float* __restrict__ dbox, const float* __restrict__ scores,
    const float2* __restrict__ aux, int mode, float* __restrict__ out) {
  const int bc = blockIdx.x;
  const int b = bc / CC, c = bc - b * CC;
  const int tid = threadIdx.x;
  float* outSlab = out + (size_t)bc * (TOPK * ROWW);

  // Zero the slab (d_out poisoned 0xAA before every call).
  {
    float4 z = make_float4(0.f, 0.f, 0.f, 0.f);
    float4* o4 = (float4*)outSlab;
    for (int i = tid; i < TOPK * ROWW / 4; i += 256) o4[i] = z;
  }
  if (c == 0) return;  // out.at[:, 0].set(0.0)

  __shared__ int hist[NBINS];
  __shared__ int chunkSum[256];
  __shared__ float cscore[CAP];
  __shared__ int cidx[CAP];
  __shared__ float bx1[TOPK], by1[TOPK], bx2[TOPK], by2[TOPK], barea[TOPK];
  __shared__ int alive[TOPK], kept[TOPK];
  __shared__ int sBT, sCnt, sKept;

  for (int i = tid; i < NBINS; i += 256) hist[i] = 0;
  if (tid == 0) { sCnt = 0; sKept = 0; }
  __syncthreads();

  const float* scoresB = scores + ((size_t)b * CC + c) * NN;  // mode 2
  const float2* auxB = aux + (size_t)b * NN;                  // mode 1
  const float* confB = conf + (size_t)b * NN * CC + c;

  // ---- pass 1: histogram on f32 score bit-pattern (monotone for s>0) ----
  for (int n = tid; n < NN; n += 256) {
    float s;
    if (mode == 2) {
      s = scoresB[n];
    } else if (mode == 1) {
      float2 a = auxB[n];
      s = (float)exp((double)(confB[(size_t)n * CC] - a.x)) / a.y;
    } else {
      const float* p = conf + ((size_t)b * NN + n) * CC;
      float e[CC], sum;
      softmax_es(p, e, sum);
      s = e[c] / sum;
    }
    if (s > 0.01f) {
      unsigned u = __float_as_uint(s);
      int bin = (int)(u >> 15) - 30720;
      bin = bin < 0 ? 0 : (bin > NBINS - 1 ? NBINS - 1 : bin);
      atomicAdd(&hist[bin], 1);
    }
  }
  __syncthreads();

  // ---- smallest bin bt whose suffix count >= TOPK ----
  {
    int s8 = 0;
#pragma unroll
    for (int k = 0; k < 8; ++k) s8 += hist[tid * 8 + k];
    chunkSum[tid] = s8;
  }
  __syncthreads();
  if (tid == 0) {
    int cum = 0, bt = 0;
    for (int ch = 255; ch >= 0; --ch) {
      if (cum + chunkSum[ch] >= TOPK) {
        for (int bin = ch * 8 + 7;; --bin) {
          cum += hist[bin];
          if (cum >= TOPK || bin == ch * 8) { bt = bin; break; }
        }
        break;
      }
      cum += chunkSum[ch];
    }
    sBT = bt;
  }
  __syncthreads();
  const int bt = sBT;

  // ---- pass 2: collect candidates (superset of exact top-200) ----
  for (int n = tid; n < NN; n += 256) {
    float s;
    if (mode == 2) {
      s = scoresB[n];
    } else if (mode == 1) {
      float2 a = auxB[n];
      s = (float)exp((double)(confB[(size_t)n * CC] - a.x)) / a.y;
    } else {
      const float* p = conf + ((size_t)b * NN + n) * CC;
      float e[CC], sum;
      softmax_es(p, e, sum);
      s = e[c] / sum;
    }
    if (s > 0.01f) {
      unsigned u = __float_as_uint(s);
      int bin = (int)(u >> 15) - 30720;
      bin = bin < 0 ? 0 : (bin > NBINS - 1 ? NBINS - 1 : bin);
      if (bin >= bt) {
        int p = atomicAdd(&sCnt, 1);
        if (p < CAP) { cscore[p] = s; cidx[p] = n; }
      }
    }
  }
  __syncthreads();
  const int M = sCnt < CAP ? sCnt : CAP;
  if (M == 0) return;

  // ---- bitonic sort by (score desc, idx asc) — matches lax.top_k ties ----
  int P = 1;
  while (P < M) P <<= 1;
  for (int i = M + tid; i < P; i += 256) {
    cscore[i] = -1e30f;
    cidx[i] = 0x7fffffff;
  }
  __syncthreads();
  for (int k = 2; k <= P; k <<= 1) {
    for (int j = k >> 1; j > 0; j >>= 1) {
      for (int i = tid; i < P; i += 256) {
        int ixj = i ^ j;
        if (ixj > i) {
          float si = cscore[i], sj = cscore[ixj];
          int ii = cidx[i], ij = cidx[ixj];
          bool agt = (si > sj) || (si == sj && ii < ij);  // i ranks before ixj
          bool up = ((i & k) == 0);
          if (up ? !agt : agt) {
            cscore[i] = sj; cscore[ixj] = si;
            cidx[i] = ij;  cidx[ixj] = ii;
          }
        }
      }
      __syncthreads();
    }
  }

  const int K = M < TOPK ? M : TOPK;

  // ---- decode candidate boxes, f32, reference op order ----
  const float* locB = loc + (size_t)b * NN * 4;
  for (int t = tid; t < K; t += 256) {
    int n = cidx[t];
    float l0 = locB[(size_t)n * 4 + 0], l1 = locB[(size_t)n * 4 + 1];
    float l2 = locB[(size_t)n * 4 + 2], l3 = locB[(size_t)n * 4 + 3];
    float d0 = dbox[(size_t)n * 4 + 0], d1 = dbox[(size_t)n * 4 + 1];
    float d2 = dbox[(size_t)n * 4 + 2], d3 = dbox[(size_t)n * 4 + 3];
    float cx = d0 + (l0 * 0.1f) * d2;
    float cy = d1 + (l1 * 0.1f) * d3;
    float w = d2 * (float)exp((double)(l2 * 0.2f));
    float h = d3 * (float)exp((double)(l3 * 0.2f));
    float x1 = cx - w * 0.5f;   // wh/2.0 == w*0.5f exactly
    float y1 = cy - h * 0.5f;
    float x2 = x1 + w;
    float y2 = y1 + h;
    bx1[t] = x1; by1[t] = y1; bx2[t] = x2; by2[t] = y2;
    barea[t] = (x2 - x1) * (y2 - y1);
    alive[t] = 1;
  }
  __syncthreads();

  // ---- greedy NMS forward scan (== argmax scan on sorted candidates) ----
  for (int j = 0; j < K; ++j) {
    __syncthreads();
    if (!alive[j]) continue;  // uniform LDS value: barrier-safe
    if (tid == 0) kept[sKept++] = j;
    float x1j = bx1[j], y1j = by1[j], x2j = bx2[j], y2j = by2[j], aj = barea[j];
    for (int l = j + 1 + tid; l < K; l += 256) {
      if (!alive[l]) continue;
      float xx1 = fmaxf(bx1[l], x1j);
      float yy1 = fmaxf(by1[l], y1j);
      float xx2 = fminf(bx2[l], x2j);
      float yy2 = fminf(by2[l], y2j);
      float iw = fmaxf(xx2 - xx1, 0.0f);
      float ih = fmaxf(yy2 - yy1, 0.0f);
      float inter = iw * ih;
      float uni = (barea[l] - inter) + aj;  // reference: area - inter + area[i]
      if (inter / uni > 0.45f) alive[l] = 0;
    }
  }
  __syncthreads();

  // ---- write kept rows: [score, box4, pose32, line3] ----
  const int nk = sKept;
  const float* poseB = pose + (size_t)b * NN * NPOSE;
  const float* lineB = line + (size_t)b * NN * NLINE;
  for (int t = tid; t < nk; t += 256) {
    int j = kept[t];
    int n = cidx[j];
    float* row = outSlab + (size_t)t * ROWW;
    row[0] = cscore[j];
    row[1] = bx1[j];
    row[2] = by1[j];
    row[3] = bx2[j];
    row[4] = by2[j];
#pragma unroll
    for (int q = 0; q < NPOSE; ++q) row[5 + q] = poseB[(size_t)n * NPOSE + q];
    row[37] = lineB[(size_t)n * NLINE + 0];
    row[38] = lineB[(size_t)n * NLINE + 1];
    row[39] = lineB[(size_t)n * NLINE + 2];
  }
}

// ---------------------------------------------------------------------------
extern "C" void kernel_launch(void* const* d_in, const int* in_sizes, int n_in,
                              void* d_out, int out_size, void* d_ws, size_t ws_size,
                              hipStream_t stream) {
  const float* loc  = (const float*)d_in[0];
  const float* conf = (const float*)d_in[1];
  const float* pose = (const float*)d_in[2];
  const float* line = (const float*)d_in[3];
  const float* dbox = (const float*)d_in[4];
  float* out = (float*)d_out;

  const size_t scoreBytes = (size_t)BB * CC * NN * sizeof(float);   // ~23.5 MB
  const size_t auxBytes   = (size_t)BB * NN * sizeof(float2);       // ~2.2 MB

  int mode;
  float* scores = nullptr;
  float2* aux = nullptr;
  if (ws_size >= scoreBytes) {
    mode = 2; scores = (float*)d_ws;
  } else if (ws_size >= auxBytes) {
    mode = 1; aux = (float2*)d_ws;
  } else {
    mode = 0;
  }

  const int total = BB * NN;
  if (mode == 2) {
    score_kernel<<<(total + 255) / 256, 256, 0, stream>>>(conf, scores);
  } else if (mode == 1) {
    aux_kernel<<<(total + 255) / 256, 256, 0, stream>>>(conf, aux);
  }
  nms_kernel<<<BB * CC, 256, 0, stream>>>(loc, conf, pose, line, dbox,
                                          scores, aux, mode, out);
}